// Round 1
// baseline (701.382 us; speedup 1.0000x reference)
//
#include <hip/hip_runtime.h>
#include <math.h>

#define TPB 256

// Kernel 1: masked per-segment partial column sums.
// grid: (col_chunks, row_chunks, B). Each thread owns 4 consecutive columns
// (float4) and walks its row chunk, then atomically adds into sums[b*D+col].
__global__ void __launch_bounds__(TPB) grit_partial_kernel(
    const float* __restrict__ hs,
    const int* __restrict__ plens,
    const int* __restrict__ ilens,
    float* __restrict__ sums,
    int B, int D, int n_row_chunks)
{
    const int b = blockIdx.z;
    const int plen = plens[b];
    const int ilen = ilens[b];

    // segment start: prefix sum of prompt_lens (B is tiny; scalar loop ok,
    // wave-uniform so it runs on the scalar unit path)
    int start = 0;
    for (int i = 0; i < b; ++i) start += plens[i];

    const int rpc = (plen + n_row_chunks - 1) / n_row_chunks;
    int r_lo = blockIdx.y * rpc;
    int r_hi = r_lo + rpc;
    if (r_hi > plen) r_hi = plen;
    if (r_lo < ilen) r_lo = ilen;   // mask out instruction tokens
    if (r_lo >= r_hi) return;

    const int col = (blockIdx.x * TPB + threadIdx.x) * 4;
    if (col >= D) return;

    const float* __restrict__ base = hs + (size_t)start * (size_t)D + col;

    float4 acc = make_float4(0.f, 0.f, 0.f, 0.f);
    for (int r = r_lo; r < r_hi; ++r) {
        const float4 v = *(const float4*)(base + (size_t)r * (size_t)D);
        acc.x += v.x;
        acc.y += v.y;
        acc.z += v.z;
        acc.w += v.w;
    }

    float* dst = sums + (size_t)b * (size_t)D + col;
    atomicAdd(dst + 0, acc.x);
    atomicAdd(dst + 1, acc.y);
    atomicAdd(dst + 2, acc.z);
    atomicAdd(dst + 3, acc.w);
}

// Kernel 2: per-sequence mean + L2 normalize. One block per sequence.
__global__ void __launch_bounds__(TPB) grit_finalize_kernel(
    const int* __restrict__ plens,
    const int* __restrict__ ilens,
    const float* __restrict__ sums,
    float* __restrict__ out,
    int D)
{
    const int b = blockIdx.x;
    const float cnt = (float)(plens[b] - ilens[b]);
    const float inv = 1.0f / cnt;

    const float* __restrict__ s = sums + (size_t)b * (size_t)D;
    float* __restrict__ o = out + (size_t)b * (size_t)D;

    // pass 1: sum of squared means
    float sq = 0.f;
    for (int col = threadIdx.x * 4; col < D; col += TPB * 4) {
        const float4 v = *(const float4*)(s + col);
        const float mx = v.x * inv, my = v.y * inv, mz = v.z * inv, mw = v.w * inv;
        sq += mx * mx + my * my + mz * mz + mw * mw;
    }

    // wave (64-lane) shuffle reduce, then cross-wave via LDS
    #pragma unroll
    for (int off = 32; off > 0; off >>= 1)
        sq += __shfl_down(sq, off, 64);

    __shared__ float wsum[TPB / 64];
    const int lane = threadIdx.x & 63;
    const int wave = threadIdx.x >> 6;
    if (lane == 0) wsum[wave] = sq;
    __syncthreads();

    float total = 0.f;
    #pragma unroll
    for (int w = 0; w < TPB / 64; ++w) total += wsum[w];

    float norm = sqrtf(total);
    norm = fmaxf(norm, 1e-12f);
    const float invn = inv / norm;   // fold mean and normalize into one scale

    // pass 2: write normalized means (sums re-read hits L2)
    for (int col = threadIdx.x * 4; col < D; col += TPB * 4) {
        const float4 v = *(const float4*)(s + col);
        float4 r;
        r.x = v.x * invn;
        r.y = v.y * invn;
        r.z = v.z * invn;
        r.w = v.w * invn;
        *(float4*)(o + col) = r;
    }
}

extern "C" void kernel_launch(void* const* d_in, const int* in_sizes, int n_in,
                              void* d_out, int out_size, void* d_ws, size_t ws_size,
                              hipStream_t stream) {
    const float* hs    = (const float*)d_in[0];
    const int*   plens = (const int*)d_in[1];
    const int*   ilens = (const int*)d_in[2];
    float*       out   = (float*)d_out;

    const int B = in_sizes[1];          // 16
    const int D = out_size / B;         // 4096

    float* sums = (float*)d_ws;         // [B, D] fp32 accumulator

    // ws is poisoned 0xAA before every launch — zero the accumulator.
    hipMemsetAsync(sums, 0, (size_t)B * (size_t)D * sizeof(float), stream);

    const int n_row_chunks = 32;        // 16*32*4 = 2048 blocks = 8 blocks/CU
    const int col_chunks = (D + TPB * 4 - 1) / (TPB * 4);
    dim3 grid(col_chunks, n_row_chunks, B);
    grit_partial_kernel<<<grid, TPB, 0, stream>>>(hs, plens, ilens, sums,
                                                  B, D, n_row_chunks);

    grit_finalize_kernel<<<B, TPB, 0, stream>>>(plens, ilens, sums, out, D);
}

// Round 2
// 676.809 us; speedup vs baseline: 1.0363x; 1.0363x over previous
//
#include <hip/hip_runtime.h>
#include <math.h>

#define TPB 256
#define ROW_CHUNKS 32

// Kernel 1: masked per-segment partial column sums, atomic-free.
// grid: (col_chunks, ROW_CHUNKS, B). Each block owns a private [TPB*4] slice
// of the partials buffer: partials[(b*ROW_CHUNKS + ry)*D + col].
// Row loop unrolled x4 with independent accumulators to keep 4
// global_load_dwordx4 in flight per thread.
__global__ void __launch_bounds__(TPB) grit_partial_kernel(
    const float* __restrict__ hs,
    const int* __restrict__ plens,
    const int* __restrict__ ilens,
    float* __restrict__ partials,
    int B, int D)
{
    const int b  = blockIdx.z;
    const int ry = blockIdx.y;
    const int plen = plens[b];
    const int ilen = ilens[b];

    // segment start: prefix sum of prompt_lens (wave-uniform, B tiny)
    int start = 0;
    for (int i = 0; i < b; ++i) start += plens[i];

    const int rpc = (plen + ROW_CHUNKS - 1) / ROW_CHUNKS;
    int r_lo = ry * rpc;
    int r_hi = r_lo + rpc;
    if (r_hi > plen) r_hi = plen;
    if (r_lo < ilen) r_lo = ilen;   // mask out instruction tokens

    const int col = (blockIdx.x * TPB + threadIdx.x) * 4;
    if (col >= D) return;

    float4 a0 = make_float4(0.f, 0.f, 0.f, 0.f);
    float4 a1 = a0, a2 = a0, a3 = a0;

    if (r_lo < r_hi) {
        const size_t stride = (size_t)D * sizeof(float);
        const char* p = (const char*)(hs + (size_t)(start + r_lo) * (size_t)D + col);
        int r = r_lo;
        for (; r + 4 <= r_hi; r += 4) {
            const float4 v0 = *(const float4*)(p);
            const float4 v1 = *(const float4*)(p + stride);
            const float4 v2 = *(const float4*)(p + 2 * stride);
            const float4 v3 = *(const float4*)(p + 3 * stride);
            p += 4 * stride;
            a0.x += v0.x; a0.y += v0.y; a0.z += v0.z; a0.w += v0.w;
            a1.x += v1.x; a1.y += v1.y; a1.z += v1.z; a1.w += v1.w;
            a2.x += v2.x; a2.y += v2.y; a2.z += v2.z; a2.w += v2.w;
            a3.x += v3.x; a3.y += v3.y; a3.z += v3.z; a3.w += v3.w;
        }
        for (; r < r_hi; ++r) {
            const float4 v = *(const float4*)(p);
            p += stride;
            a0.x += v.x; a0.y += v.y; a0.z += v.z; a0.w += v.w;
        }
    }

    float4 t;
    t.x = (a0.x + a1.x) + (a2.x + a3.x);
    t.y = (a0.y + a1.y) + (a2.y + a3.y);
    t.z = (a0.z + a1.z) + (a2.z + a3.z);
    t.w = (a0.w + a1.w) + (a2.w + a3.w);

    // always write (even zeros): ws is poisoned 0xAA before every launch
    *(float4*)(partials + (size_t)(b * ROW_CHUNKS + ry) * (size_t)D + col) = t;
}

// Kernel 2: reduce 32 chunk-partials, mean, L2 normalize. One block per seq.
__global__ void __launch_bounds__(TPB) grit_finalize_kernel(
    const int* __restrict__ plens,
    const int* __restrict__ ilens,
    const float* __restrict__ partials,
    float* __restrict__ out,
    int D)
{
    const int b = blockIdx.x;
    const float inv = 1.0f / (float)(plens[b] - ilens[b]);

    const float* __restrict__ p = partials + (size_t)b * ROW_CHUNKS * (size_t)D;
    float* __restrict__ o = out + (size_t)b * (size_t)D;

    // pass 1: chunk-reduce to mean, write mean to out, accumulate sumsq
    float sq = 0.f;
    for (int col = threadIdx.x * 4; col < D; col += TPB * 4) {
        float4 s = make_float4(0.f, 0.f, 0.f, 0.f);
        #pragma unroll
        for (int ry = 0; ry < ROW_CHUNKS; ++ry) {
            const float4 v = *(const float4*)(p + (size_t)ry * (size_t)D + col);
            s.x += v.x; s.y += v.y; s.z += v.z; s.w += v.w;
        }
        float4 m;
        m.x = s.x * inv; m.y = s.y * inv; m.z = s.z * inv; m.w = s.w * inv;
        sq += m.x * m.x + m.y * m.y + m.z * m.z + m.w * m.w;
        *(float4*)(o + col) = m;
    }

    // wave shuffle reduce, then cross-wave via LDS
    #pragma unroll
    for (int off = 32; off > 0; off >>= 1)
        sq += __shfl_down(sq, off, 64);

    __shared__ float wsum[TPB / 64];
    const int lane = threadIdx.x & 63;
    const int wave = threadIdx.x >> 6;
    if (lane == 0) wsum[wave] = sq;
    __syncthreads();

    float total = 0.f;
    #pragma unroll
    for (int w = 0; w < TPB / 64; ++w) total += wsum[w];

    const float invn = 1.0f / fmaxf(sqrtf(total), 1e-12f);

    // pass 2: rescale out in place (L2-hot, 16 KiB per block)
    for (int col = threadIdx.x * 4; col < D; col += TPB * 4) {
        const float4 m = *(const float4*)(o + col);
        float4 r;
        r.x = m.x * invn; r.y = m.y * invn; r.z = m.z * invn; r.w = m.w * invn;
        *(float4*)(o + col) = r;
    }
}

extern "C" void kernel_launch(void* const* d_in, const int* in_sizes, int n_in,
                              void* d_out, int out_size, void* d_ws, size_t ws_size,
                              hipStream_t stream) {
    const float* hs    = (const float*)d_in[0];
    const int*   plens = (const int*)d_in[1];
    const int*   ilens = (const int*)d_in[2];
    float*       out   = (float*)d_out;

    const int B = in_sizes[1];          // 16
    const int D = out_size / B;         // 4096

    float* partials = (float*)d_ws;     // [B*ROW_CHUNKS, D] fp32

    const int col_chunks = (D + TPB * 4 - 1) / (TPB * 4);   // 4
    dim3 grid(col_chunks, ROW_CHUNKS, B);                   // 2048 blocks
    grit_partial_kernel<<<grid, TPB, 0, stream>>>(hs, plens, ilens, partials, B, D);

    grit_finalize_kernel<<<B, TPB, 0, stream>>>(plens, ilens, partials, out, D);
}